// Round 9
// baseline (280.528 us; speedup 1.0000x reference)
//
#include <hip/hip_runtime.h>

#define LQg 2048
#define LKg 2048
#define DDg 256
#define NBg 16
#define KVB 32
#define NTILES 64   // LKg / KVB
#define TSH 14      // 16 KB per image tile (K: 32x512B, V: 256x64B)

typedef unsigned int uint;
typedef unsigned short ushort;
typedef unsigned char uchar;
typedef __attribute__((ext_vector_type(8))) __bf16 bf16x8;
typedef __attribute__((ext_vector_type(16))) float f32x16;

static __device__ __forceinline__ uint pack2(float a, float b) {
    ushort ua = __builtin_bit_cast(ushort, (__bf16)a);
    ushort ub = __builtin_bit_cast(ushort, (__bf16)b);
    return (uint)ua | ((uint)ub << 16);
}

static __device__ __forceinline__ f32x16 mfma32(bf16x8 a, bf16x8 b, f32x16 c) {
    return __builtin_amdgcn_mfma_f32_32x32x16_bf16(a, b, c, 0, 0, 0);
}

// async global->LDS, 16B per lane
typedef const __attribute__((address_space(1))) uchar* gas_t;
typedef __attribute__((address_space(3))) uchar* las_t;
static __device__ __forceinline__ void gl_lds16(const void* g, void* l) {
    __builtin_amdgcn_global_load_lds((gas_t)g, (las_t)l, 16, 0, 0);
}

// ---------------- prep: K -> bf16 image (tiles 32x512B, 16B-chunk XOR swizzle) ----
// (r5/r6-verified byte layout)
__global__ __launch_bounds__(256) void prep_k(const float* __restrict__ K,
                                              uchar* __restrict__ Kimg) {
    const uint gid = blockIdx.x * 256 + threadIdx.x;
    const uint d8 = gid & 31;
    const uint row = (gid >> 5) & 31;
    const uint t = (gid >> 10) & 63;
    const uint b = gid >> 16;
    const float* src = K + (((size_t)b * LKg + t * KVB + row) * DDg + d8 * 8);
    float4 a = *(const float4*)src;
    float4 c = *(const float4*)(src + 4);
    uint4 u;
    u.x = pack2(a.x, a.y); u.y = pack2(a.z, a.w);
    u.z = pack2(c.x, c.y); u.w = pack2(c.z, c.w);
    const size_t base = ((size_t)(b * NTILES + t)) << TSH;
    const uint off = row * 512 + ((d8 * 16) ^ ((row & 7) << 4));
    *(uint4*)(Kimg + base + off) = u;
}

// ------- prep: V -> bf16 transposed image [dv][32k*2B=64B], dword-rotated -------
// k-pair p of row dv at byte (4p + 4*((dv>>1)&15)) & 63  (r5/r6-verified)
__global__ __launch_bounds__(256) void prep_v(const float* __restrict__ V,
                                              uchar* __restrict__ Vimg) {
    const uint gid = blockIdx.x * 256 + threadIdx.x;
    const uint dv = gid & 255;
    const uint t = (gid >> 8) & 63;
    const uint b = gid >> 14;
    const uint rot = 4 * ((dv >> 1) & 15);
    uchar* base = Vimg + (((size_t)(b * NTILES + t)) << TSH) + dv * 64;
    const float* src = V + ((size_t)b * LKg + t * KVB) * DDg + dv;
#pragma unroll
    for (int kq = 0; kq < 8; ++kq) {
        float v0 = src[(kq * 4 + 0) * DDg];
        float v1 = src[(kq * 4 + 1) * DDg];
        float v2 = src[(kq * 4 + 2) * DDg];
        float v3 = src[(kq * 4 + 3) * DDg];
        const uint o = (8 * kq + rot) & 63;
        *(uint*)(base + o) = pack2(v0, v1);
        *(uint*)(base + ((o + 4) & 63)) = pack2(v2, v3);
    }
}

// ---------------- suffix-sum of V over [32-aligned boundary, 2048) ----------------
__global__ void tv_partial_k(const float* __restrict__ V, const int* __restrict__ vlen,
                             float* __restrict__ part) {
    const int c = blockIdx.x, b = blockIdx.y, t = threadIdx.x;
    const int vl = vlen[b];
    int bnd = ((vl + 31) >> 5) << 5;
    if (bnd > LKg) bnd = LKg;
    const int k0 = c * 128, k1 = k0 + 128;
    int lo = k0 > bnd ? k0 : bnd;
    float s = 0.f;
    for (int k = lo; k < k1; ++k) s += V[((size_t)(b * LKg + k)) * DDg + t];
    part[(size_t)(b * 16 + c) * DDg + t] = s;
}

__global__ void tv_reduce_k(const float* __restrict__ part, float* __restrict__ TV) {
    const int b = blockIdx.x, t = threadIdx.x;
    float s = 0.f;
    for (int c = 0; c < 16; ++c) s += part[(size_t)(b * 16 + c) * DDg + t];
    TV[b * DDg + t] = s;
}

// -- main: 4 waves, 128 q/block; IMG=1: DV-SPLIT over blockIdx.y (acc 64 VGPR, 48KB LDS)
template <int IMG>
__global__ __launch_bounds__(256, 1) void attn_k(
    const float* __restrict__ Qg, const float* __restrict__ Kg,
    const float* __restrict__ Vg, const uchar* __restrict__ Kimg,
    const uchar* __restrict__ Vimg, const int* __restrict__ vlen,
    const float* __restrict__ TV, float* __restrict__ Og, int use_tail) {
    constexpr int NDT = IMG ? 4 : 8;          // dv sub-tiles per block
    constexpr int VROWS = IMG ? 128 : 256;    // sV rows
    __shared__ alignas(16) uchar sK[2][KVB * 512];    // 2 x 16 KB
    __shared__ alignas(16) uchar sV[2][VROWS * 64];   // 2 x (8 or 16) KB

    const int tid = threadIdx.x;
    const int lane = tid & 63;
    const int w = tid >> 6;
    const int lq = lane & 31;
    const int h = lane >> 5;
    const int qb = blockIdx.x & 15;   // qb-inner: consecutive blocks share KV
    const int b = blockIdx.x >> 4;
    const int dvh = IMG ? blockIdx.y : 0;   // dv half
    const int q = qb * 128 + w * 32 + lq;
    const int vl = vlen[b];

    const float SCALE = 0.09016844136f;  // (1/sqrt(256)) * log2(e)

    const int nt = use_tail ? ((vl + KVB - 1) / KVB) : NTILES;
    const int swzK = (lq & 7) << 4;
    const int rotv = (lq >> 1) * 4;

    // convoy-breaking tile rotation (online softmax is order-invariant)
    const int ph = ((qb ^ b ^ dvh) & 1) ? (nt >> 1) : 0;
    const int ts0 = ph;

    // ---- prologue: stage tile ts0 ----
    int cur = 0;
    if (IMG) {
        const uchar* gK = Kimg + (((size_t)(b * NTILES + ts0)) << TSH) + tid * 16;
        const uchar* gV = Vimg + (((size_t)(b * NTILES + ts0)) << TSH) + dvh * 8192 + tid * 16;
#pragma unroll
        for (int i = 0; i < 4; ++i) gl_lds16(gK + i * 4096, &sK[0][i * 4096 + tid * 16]);
#pragma unroll
        for (int i = 0; i < 2; ++i) gl_lds16(gV + i * 4096, &sV[0][i * 4096 + tid * 16]);
    }

    // ---- Q fragments (overlaps staging latency) ----
    bf16x8 qf[16];
    {
        const float* qp = Qg + ((size_t)(b * LQg + q)) * DDg + h * 8;
#pragma unroll
        for (int c = 0; c < 16; ++c) {
            float4 a = *(const float4*)(qp + c * 16);
            float4 bb = *(const float4*)(qp + c * 16 + 4);
            uint4 u;
            u.x = pack2(a.x * SCALE, a.y * SCALE);
            u.y = pack2(a.z * SCALE, a.w * SCALE);
            u.z = pack2(bb.x * SCALE, bb.y * SCALE);
            u.w = pack2(bb.z * SCALE, bb.w * SCALE);
            qf[c] = __builtin_bit_cast(bf16x8, u);
        }
    }

    // non-image staging (fallback), tile ts0 (full dv)
    if (!IMG && nt > 0) {
#pragma unroll
        for (int i = 0; i < 4; ++i) {
            const int cid = i * 256 + tid;
            const int d8 = cid & 31, row = cid >> 5;
            const float* src = Kg + (((size_t)b * LKg + ts0 * KVB + row) * DDg + d8 * 8);
            float4 a = *(const float4*)src;
            float4 c = *(const float4*)(src + 4);
            uint4 u;
            u.x = pack2(a.x, a.y); u.y = pack2(a.z, a.w);
            u.z = pack2(c.x, c.y); u.w = pack2(c.z, c.w);
            *(uint4*)(&sK[0][row * 512 + ((d8 * 16) ^ ((row & 7) << 4))]) = u;
        }
        {
            const int dv = tid;
            const uint rot = 4 * ((dv >> 1) & 15);
            const float* src = Vg + ((size_t)b * LKg + ts0 * KVB) * DDg + dv;
            uchar* dst = &sV[0][dv * 64];
#pragma unroll
            for (int kq = 0; kq < 8; ++kq) {
                float v0 = src[(kq * 4 + 0) * DDg];
                float v1 = src[(kq * 4 + 1) * DDg];
                float v2 = src[(kq * 4 + 2) * DDg];
                float v3 = src[(kq * 4 + 3) * DDg];
                const uint o = (8 * kq + rot) & 63;
                *(uint*)(dst + o) = pack2(v0, v1);
                *(uint*)(dst + ((o + 4) & 63)) = pack2(v2, v3);
            }
        }
    }

    f32x16 acc[NDT];
#pragma unroll
    for (int i = 0; i < NDT; ++i)
#pragma unroll
        for (int j = 0; j < 16; ++j) acc[i][j] = 0.f;

    float m = -1e30f, ell = 0.f;

    __syncthreads();   // drains vmcnt (gl_lds) + lds writes

    int tt = ts0;
    for (int i = 0; i < nt; ++i) {
        const int tn = (tt + 1 == nt) ? 0 : tt + 1;
        const int k0 = tt * KVB;

        // ---- prefetch next tile into the other buffer ----
        if (i + 1 < nt) {
            if (IMG) {
                const uchar* gK = Kimg + (((size_t)(b * NTILES + tn)) << TSH) + tid * 16;
                const uchar* gV = Vimg + (((size_t)(b * NTILES + tn)) << TSH) + dvh * 8192 + tid * 16;
#pragma unroll
                for (int j = 0; j < 4; ++j) gl_lds16(gK + j * 4096, &sK[cur ^ 1][j * 4096 + tid * 16]);
#pragma unroll
                for (int j = 0; j < 2; ++j) gl_lds16(gV + j * 4096, &sV[cur ^ 1][j * 4096 + tid * 16]);
            } else {
                const int k1 = tn * KVB;
#pragma unroll
                for (int j = 0; j < 4; ++j) {
                    const int cid = j * 256 + tid;
                    const int d8 = cid & 31, row = cid >> 5;
                    const float* src = Kg + (((size_t)b * LKg + k1 + row) * DDg + d8 * 8);
                    float4 a = *(const float4*)src;
                    float4 c = *(const float4*)(src + 4);
                    uint4 u;
                    u.x = pack2(a.x, a.y); u.y = pack2(a.z, a.w);
                    u.z = pack2(c.x, c.y); u.w = pack2(c.z, c.w);
                    *(uint4*)(&sK[cur ^ 1][row * 512 + ((d8 * 16) ^ ((row & 7) << 4))]) = u;
                }
                {
                    const int dv = tid;
                    const uint rot = 4 * ((dv >> 1) & 15);
                    const float* src = Vg + ((size_t)b * LKg + k1) * DDg + dv;
                    uchar* dst = &sV[cur ^ 1][dv * 64];
#pragma unroll
                    for (int kq = 0; kq < 8; ++kq) {
                        float v0 = src[(kq * 4 + 0) * DDg];
                        float v1 = src[(kq * 4 + 1) * DDg];
                        float v2 = src[(kq * 4 + 2) * DDg];
                        float v3 = src[(kq * 4 + 3) * DDg];
                        const uint o = (8 * kq + rot) & 63;
                        *(uint*)(dst + o) = pack2(v0, v1);
                        *(uint*)(dst + ((o + 4) & 63)) = pack2(v2, v3);
                    }
                }
            }
        }

        // ---- QK^T as S^T = mfma(K, Q^T); two 8-deep accumulate chains ----
        const uchar* sKc = sK[cur];
        const uchar* sVc = sV[cur];
        f32x16 s0a, s0b;
#pragma unroll
        for (int j = 0; j < 16; ++j) { s0a[j] = 0.f; s0b[j] = 0.f; }
        __builtin_amdgcn_s_setprio(1);
#pragma unroll
        for (int c = 0; c < 8; ++c) {
            bf16x8 kfa = *(const bf16x8*)(sKc + lq * 512 + (((2 * c) * 32 + h * 16) ^ swzK));
            bf16x8 kfb = *(const bf16x8*)(sKc + lq * 512 + (((2 * c + 1) * 32 + h * 16) ^ swzK));
            s0a = mfma32(kfa, qf[2 * c], s0a);
            s0b = mfma32(kfb, qf[2 * c + 1], s0b);
        }
        __builtin_amdgcn_s_setprio(0);
        f32x16 s0 = s0a + s0b;

        // ---- mask (masked score := 0, matching the reference) ----
        if (k0 + KVB > vl) {
            const int kb0 = k0 + 4 * h;
#pragma unroll
            for (int r = 0; r < 16; ++r) {
                const int key0 = kb0 + (r & 3) + 8 * (r >> 2);
                if (key0 >= vl) s0[r] = 0.f;
            }
        }

        // ---- online softmax; pair-consistent m/ell (shfl_xor: HW-verified) ----
        float mt = s0[0];
#pragma unroll
        for (int r = 1; r < 16; ++r) mt = fmaxf(mt, s0[r]);
        mt = fmaxf(mt, __shfl_xor(mt, 32));
        if (mt > m + 8.f) {
            const float mn = fmaxf(m, mt);
            const float sf = exp2f(m - mn);
            ell *= sf;
#pragma unroll
            for (int i2 = 0; i2 < NDT; ++i2) acc[i2] *= sf;
            m = mn;
        }
        float rs = 0.f;
#pragma unroll
        for (int r = 0; r < 16; ++r) { s0[r] = exp2f(s0[r] - m); rs += s0[r]; }
        rs += __shfl_xor(rs, 32);
        ell += rs;

        // ---- build P^T B-fragments (half-exchange via shfl_xor 32; verified) ----
        bf16x8 pf[2];
#pragma unroll
        for (int kc = 0; kc < 2; ++kc) {
            const int bb = kc * 8;
            uint w0 = pack2(s0[bb + 0], s0[bb + 1]);
            uint w1 = pack2(s0[bb + 2], s0[bb + 3]);
            uint w2 = pack2(s0[bb + 4], s0[bb + 5]);
            uint w3 = pack2(s0[bb + 6], s0[bb + 7]);
            uint e0 = __shfl_xor(w0, 32);
            uint e1 = __shfl_xor(w1, 32);
            uint e2 = __shfl_xor(w2, 32);
            uint e3 = __shfl_xor(w3, 32);
            uint4 u;
            u.x = h ? e2 : w0;
            u.y = h ? e3 : w1;
            u.z = h ? w2 : e0;
            u.w = h ? w3 : e1;
            pf[kc] = __builtin_bit_cast(bf16x8, u);
        }

        // ---- PV: O^T += mfma(V^T, P^T); 4 x b32 per-dword-wrap reads (verified) ----
        __builtin_amdgcn_s_setprio(1);
#pragma unroll
        for (int kc = 0; kc < 2; ++kc) {
            const int kk = kc * 16 + h * 8;
            const uint o0 = (uint)((2 * kk + rotv) & 63);
            const uint o1 = (uint)((2 * kk + 4 + rotv) & 63);
            const uint o2 = (uint)((2 * kk + 8 + rotv) & 63);
            const uint o3 = (uint)((2 * kk + 12 + rotv) & 63);
#pragma unroll
            for (int dt = 0; dt < NDT; ++dt) {
                const uchar* base = sVc + dt * 2048 + lq * 64;
                uint4 u;
                u.x = *(const uint*)(base + o0);
                u.y = *(const uint*)(base + o1);
                u.z = *(const uint*)(base + o2);
                u.w = *(const uint*)(base + o3);
                acc[dt] = mfma32(__builtin_bit_cast(bf16x8, u), pf[kc], acc[dt]);
            }
        }
        __builtin_amdgcn_s_setprio(0);

        __syncthreads();   // implicit vmcnt(0): next tile staged; reads of cur done
        cur ^= 1;
        tt = tn;
    }

    // ---- analytic masked tail: scores are exactly 0 there ----
    if (use_tail) {
        const int bnd = nt * KVB;
        const int cnt = LKg - bnd;
        if (cnt > 0) {
            if (m < -8.f) {
                const float sf = exp2f(m);
                ell *= sf;
#pragma unroll
                for (int i = 0; i < NDT; ++i) acc[i] *= sf;
                m = 0.f;
            }
            const float pt = exp2f(-m);
            ell += (float)cnt * pt;
            const float* tp = TV + b * DDg + dvh * 128 + h * 4;
#pragma unroll
            for (int dt = 0; dt < NDT; ++dt) {
#pragma unroll
                for (int rg = 0; rg < 4; ++rg) {
                    float4 tv = *(const float4*)(tp + dt * 32 + rg * 8);
                    acc[dt][rg * 4 + 0] += pt * tv.x;
                    acc[dt][rg * 4 + 1] += pt * tv.y;
                    acc[dt][rg * 4 + 2] += pt * tv.z;
                    acc[dt][rg * 4 + 3] += pt * tv.w;
                }
            }
        }
    }

    // ---- epilogue: O = O^T(lane-local column) / ell ----
    const float inv = 1.f / ell;
    float* op = Og + ((size_t)(b * LQg + q)) * DDg + dvh * 128 + h * 4;
#pragma unroll
    for (int dt = 0; dt < NDT; ++dt) {
#pragma unroll
        for (int rg = 0; rg < 4; ++rg) {
            float4 o;
            o.x = acc[dt][rg * 4 + 0] * inv;
            o.y = acc[dt][rg * 4 + 1] * inv;
            o.z = acc[dt][rg * 4 + 2] * inv;
            o.w = acc[dt][rg * 4 + 3] * inv;
            *(float4*)(op + dt * 32 + rg * 8) = o;
        }
    }
}

extern "C" void kernel_launch(void* const* d_in, const int* in_sizes, int n_in,
                              void* d_out, int out_size, void* d_ws, size_t ws_size,
                              hipStream_t stream) {
    const float* Q = (const float*)d_in[0];
    const float* K = (const float*)d_in[1];
    const float* V = (const float*)d_in[2];
    const int* vlen = (const int*)d_in[3];
    float* out = (float*)d_out;

    // ws layout: part(256KB) | TV(pad 256KB) | Kimg(16MB) | Vimg(16MB)
    const size_t off_part = 0;
    const size_t off_TV = 262144;
    const size_t off_K = 524288;
    const size_t imgsz = (size_t)NBg * NTILES << TSH;   // 16 MB
    const size_t off_V = off_K + imgsz;
    const size_t need_tail = off_TV + (size_t)NBg * DDg * 4;
    const size_t need_img = off_V + imgsz;              // 32.5 MB (proven fits)

    const int use_tail = (ws_size >= need_tail) ? 1 : 0;
    const int use_img = (ws_size >= need_img) ? 1 : 0;

    float* part = (float*)((char*)d_ws + off_part);
    float* TV = (float*)((char*)d_ws + off_TV);
    uchar* Kimg = (uchar*)d_ws + off_K;
    uchar* Vimg = (uchar*)d_ws + off_V;

    if (use_tail) {
        tv_partial_k<<<dim3(16, 16), 256, 0, stream>>>(V, vlen, part);
        tv_reduce_k<<<dim3(16), 256, 0, stream>>>(part, TV);
    }
    if (use_img) {
        prep_k<<<dim3(4096), 256, 0, stream>>>(K, Kimg);
        prep_v<<<dim3(1024), 256, 0, stream>>>(V, Vimg);
        // dv-split: 512 blocks, 48 KB LDS, ~190 VGPR -> 2 blocks/CU, 2 waves/SIMD
        attn_k<1><<<dim3(256, 2), 256, 0, stream>>>(Q, K, V, Kimg, Vimg, vlen, TV, out, use_tail);
    } else {
        attn_k<0><<<dim3(256, 1), 256, 0, stream>>>(Q, K, V, Kimg, Vimg, vlen, TV, out, use_tail);
    }
}

// Round 10
// 261.701 us; speedup vs baseline: 1.0719x; 1.0719x over previous
//
#include <hip/hip_runtime.h>

#define LQg 2048
#define LKg 2048
#define DDg 256
#define NBg 16
#define KVB 32
#define NTILES 64   // LKg / KVB
#define TSH 14      // 16 KB per image tile (K: 32x512B, V: 256x64B)

typedef unsigned int uint;
typedef unsigned short ushort;
typedef unsigned char uchar;
typedef __attribute__((ext_vector_type(8))) __bf16 bf16x8;
typedef __attribute__((ext_vector_type(16))) float f32x16;

static __device__ __forceinline__ uint pack2(float a, float b) {
    ushort ua = __builtin_bit_cast(ushort, (__bf16)a);
    ushort ub = __builtin_bit_cast(ushort, (__bf16)b);
    return (uint)ua | ((uint)ub << 16);
}

static __device__ __forceinline__ f32x16 mfma32(bf16x8 a, bf16x8 b, f32x16 c) {
    return __builtin_amdgcn_mfma_f32_32x32x16_bf16(a, b, c, 0, 0, 0);
}

// ---------------- prep: K -> bf16 image, plain rows (tiles 32 x 512B) ----------
__global__ __launch_bounds__(256) void prep_k(const float* __restrict__ K,
                                              uchar* __restrict__ Kimg) {
    const uint gid = blockIdx.x * 256 + threadIdx.x;   // one 16B chunk (8 d-elems)
    const uint d8 = gid & 31;
    const uint row = (gid >> 5) & 31;
    const uint t = (gid >> 10) & 63;
    const uint b = gid >> 16;
    const float* src = K + (((size_t)b * LKg + t * KVB + row) * DDg + d8 * 8);
    float4 a = *(const float4*)src;
    float4 c = *(const float4*)(src + 4);
    uint4 u;
    u.x = pack2(a.x, a.y); u.y = pack2(a.z, a.w);
    u.z = pack2(c.x, c.y); u.w = pack2(c.z, c.w);
    const size_t base = ((size_t)(b * NTILES + t)) << TSH;
    *(uint4*)(Kimg + base + row * 512 + d8 * 16) = u;
}

// ------- prep: V -> bf16 transposed image, plain rows [dv][32k * 2B = 64B] -------
__global__ __launch_bounds__(256) void prep_v(const float* __restrict__ V,
                                              uchar* __restrict__ Vimg) {
    const uint gid = blockIdx.x * 256 + threadIdx.x;   // one dv-row of one tile
    const uint dv = gid & 255;
    const uint t = (gid >> 8) & 63;
    const uint b = gid >> 14;
    uchar* base = Vimg + (((size_t)(b * NTILES + t)) << TSH) + dv * 64;
    const float* src = V + ((size_t)b * LKg + t * KVB) * DDg + dv;
#pragma unroll
    for (int kq = 0; kq < 8; ++kq) {
        float v0 = src[(kq * 4 + 0) * DDg];
        float v1 = src[(kq * 4 + 1) * DDg];
        float v2 = src[(kq * 4 + 2) * DDg];
        float v3 = src[(kq * 4 + 3) * DDg];
        uint2 uu; uu.x = pack2(v0, v1); uu.y = pack2(v2, v3);
        *(uint2*)(base + 8 * kq) = uu;
    }
}

// ---------------- suffix-sum of V over [32-aligned boundary, 2048) ----------------
__global__ void tv_partial_k(const float* __restrict__ V, const int* __restrict__ vlen,
                             float* __restrict__ part) {
    const int c = blockIdx.x, b = blockIdx.y, t = threadIdx.x;
    const int vl = vlen[b];
    int bnd = ((vl + 31) >> 5) << 5;
    if (bnd > LKg) bnd = LKg;
    const int k0 = c * 128, k1 = k0 + 128;
    int lo = k0 > bnd ? k0 : bnd;
    float s = 0.f;
    for (int k = lo; k < k1; ++k) s += V[((size_t)(b * LKg + k)) * DDg + t];
    part[(size_t)(b * 16 + c) * DDg + t] = s;
}

__global__ void tv_reduce_k(const float* __restrict__ part, float* __restrict__ TV) {
    const int b = blockIdx.x, t = threadIdx.x;
    float s = 0.f;
    for (int c = 0; c < 16; ++c) s += part[(size_t)(b * 16 + c) * DDg + t];
    TV[b * DDg + t] = s;
}

// ----- main (image path): 1 wave / 64-thr block, NO LDS, NO barriers.
// Waves run free; K/V frags read straight from L2-resident images with the
// same (verified) offset arithmetic the LDS path used, swizzles dropped both sides.
__global__ __launch_bounds__(64, 1) void attn_img_k(
    const float* __restrict__ Qg, const uchar* __restrict__ Kimg,
    const uchar* __restrict__ Vimg, const int* __restrict__ vlen,
    const float* __restrict__ TV, float* __restrict__ Og, int use_tail) {
    const int lane = threadIdx.x;
    const int lq = lane & 31;
    const int h = lane >> 5;
    const int b = blockIdx.x & 15;     // batch-interleaved: per-CU work mixing
    const int qw = blockIdx.x >> 4;    // 0..63, 32 q-rows each
    const int q = qw * 32 + lq;
    const int vl = vlen[b];

    const float SCALE = 0.09016844136f;  // (1/sqrt(256)) * log2(e); exp2 domain
    const int nt = use_tail ? ((vl + KVB - 1) / KVB) : NTILES;

    // ---- Q fragments in registers (pre-scaled bf16) ----
    bf16x8 qf[16];
    {
        const float* qp = Qg + ((size_t)(b * LQg + q)) * DDg + h * 8;
#pragma unroll
        for (int c = 0; c < 16; ++c) {
            float4 a = *(const float4*)(qp + c * 16);
            float4 bb = *(const float4*)(qp + c * 16 + 4);
            uint4 u;
            u.x = pack2(a.x * SCALE, a.y * SCALE);
            u.y = pack2(a.z * SCALE, a.w * SCALE);
            u.z = pack2(bb.x * SCALE, bb.y * SCALE);
            u.w = pack2(bb.z * SCALE, bb.w * SCALE);
            qf[c] = __builtin_bit_cast(bf16x8, u);
        }
    }

    f32x16 acc[8];
#pragma unroll
    for (int i = 0; i < 8; ++i)
#pragma unroll
        for (int j = 0; j < 16; ++j) acc[i][j] = 0.f;

    float m = -1e30f, ell = 0.f;

    const uchar* gKb = Kimg + ((size_t)(b * NTILES) << TSH) + lq * 512 + h * 16;
    const uchar* gVb = Vimg + ((size_t)(b * NTILES) << TSH) + lq * 64 + h * 16;

    for (int t = 0; t < nt; ++t) {
        const int k0 = t * KVB;
        const uchar* gK = gKb + ((size_t)t << TSH);
        const uchar* gV = gVb + ((size_t)t << TSH);

        // ---- QK^T as S^T = mfma(K, Q^T): pair (l, l+32) holds P-row for q ----
        f32x16 s0;
#pragma unroll
        for (int j = 0; j < 16; ++j) s0[j] = 0.f;
#pragma unroll
        for (int c = 0; c < 16; ++c) {
            bf16x8 kf = *(const bf16x8*)(gK + c * 32);
            s0 = mfma32(kf, qf[c], s0);
        }

        // ---- mask (masked score := 0, matching the reference) ----
        if (k0 + KVB > vl) {
            const int kb0 = k0 + 4 * h;
#pragma unroll
            for (int r = 0; r < 16; ++r) {
                const int key0 = kb0 + (r & 3) + 8 * (r >> 2);
                if (key0 >= vl) s0[r] = 0.f;
            }
        }

        // ---- online softmax; pair-consistent m/ell (shfl_xor: HW-verified) ----
        float mt = s0[0];
#pragma unroll
        for (int r = 1; r < 16; ++r) mt = fmaxf(mt, s0[r]);
        mt = fmaxf(mt, __shfl_xor(mt, 32));
        if (mt > m + 8.f) {
            const float mn = fmaxf(m, mt);
            const float sf = exp2f(m - mn);
            ell *= sf;
#pragma unroll
            for (int i2 = 0; i2 < 8; ++i2) acc[i2] *= sf;
            m = mn;
        }
        float rs = 0.f;
#pragma unroll
        for (int r = 0; r < 16; ++r) { s0[r] = exp2f(s0[r] - m); rs += s0[r]; }
        rs += __shfl_xor(rs, 32);
        ell += rs;

        // ---- build P^T B-fragments (half-exchange via shfl_xor 32; verified) ----
        bf16x8 pf[2];
#pragma unroll
        for (int kc = 0; kc < 2; ++kc) {
            const int bb = kc * 8;
            uint w0 = pack2(s0[bb + 0], s0[bb + 1]);
            uint w1 = pack2(s0[bb + 2], s0[bb + 3]);
            uint w2 = pack2(s0[bb + 4], s0[bb + 5]);
            uint w3 = pack2(s0[bb + 6], s0[bb + 7]);
            uint e0 = __shfl_xor(w0, 32);
            uint e1 = __shfl_xor(w1, 32);
            uint e2 = __shfl_xor(w2, 32);
            uint e3 = __shfl_xor(w3, 32);
            uint4 u;
            u.x = h ? e2 : w0;
            u.y = h ? e3 : w1;
            u.z = h ? w2 : e0;
            u.w = h ? w3 : e1;
            pf[kc] = __builtin_bit_cast(bf16x8, u);
        }

        // ---- PV: O^T += mfma(V^T, P^T); one 16B load per (kc,dt) ----
#pragma unroll
        for (int kc = 0; kc < 2; ++kc) {
#pragma unroll
            for (int dt = 0; dt < 8; ++dt) {
                uint4 u = *(const uint4*)(gV + dt * 2048 + kc * 32);
                acc[dt] = mfma32(__builtin_bit_cast(bf16x8, u), pf[kc], acc[dt]);
            }
        }
    }

    // ---- analytic masked tail: scores are exactly 0 there ----
    if (use_tail) {
        const int bnd = nt * KVB;
        const int cnt = LKg - bnd;
        if (cnt > 0) {
            if (m < -8.f) {
                const float sf = exp2f(m);
                ell *= sf;
#pragma unroll
                for (int i = 0; i < 8; ++i) acc[i] *= sf;
                m = 0.f;
            }
            const float pt = exp2f(-m);
            ell += (float)cnt * pt;
            const float* tp = TV + b * DDg + h * 4;
#pragma unroll
            for (int dt = 0; dt < 8; ++dt) {
#pragma unroll
                for (int rg = 0; rg < 4; ++rg) {
                    float4 tv = *(const float4*)(tp + dt * 32 + rg * 8);
                    acc[dt][rg * 4 + 0] += pt * tv.x;
                    acc[dt][rg * 4 + 1] += pt * tv.y;
                    acc[dt][rg * 4 + 2] += pt * tv.z;
                    acc[dt][rg * 4 + 3] += pt * tv.w;
                }
            }
        }
    }

    // ---- epilogue: O = O^T(lane-local column) / ell ----
    const float inv = 1.f / ell;
    float* op = Og + ((size_t)(b * LQg + q)) * DDg + h * 4;
#pragma unroll
    for (int dt = 0; dt < 8; ++dt) {
#pragma unroll
        for (int rg = 0; rg < 4; ++rg) {
            float4 o;
            o.x = acc[dt][rg * 4 + 0] * inv;
            o.y = acc[dt][rg * 4 + 1] * inv;
            o.z = acc[dt][rg * 4 + 2] * inv;
            o.w = acc[dt][rg * 4 + 3] * inv;
            *(float4*)(op + dt * 32 + rg * 8) = o;
        }
    }
}

// ----- fallback (no workspace for images): r8-verified LDS path, 4 waves ---------
__global__ __launch_bounds__(256, 1) void attn_fb_k(
    const float* __restrict__ Qg, const float* __restrict__ Kg,
    const float* __restrict__ Vg, const int* __restrict__ vlen,
    const float* __restrict__ TV, float* __restrict__ Og, int use_tail) {
    __shared__ alignas(16) uchar sK[2][KVB * 512];
    __shared__ alignas(16) uchar sV[2][256 * 64];

    const int tid = threadIdx.x;
    const int lane = tid & 63;
    const int w = tid >> 6;
    const int lq = lane & 31;
    const int h = lane >> 5;
    const int qb = blockIdx.x & 15;
    const int b = blockIdx.x >> 4;
    const int q = qb * 128 + w * 32 + lq;
    const int vl = vlen[b];

    const float SCALE = 0.09016844136f;
    const int nt = use_tail ? ((vl + KVB - 1) / KVB) : NTILES;

    bf16x8 qf[16];
    {
        const float* qp = Qg + ((size_t)(b * LQg + q)) * DDg + h * 8;
#pragma unroll
        for (int c = 0; c < 16; ++c) {
            float4 a = *(const float4*)(qp + c * 16);
            float4 bb = *(const float4*)(qp + c * 16 + 4);
            uint4 u;
            u.x = pack2(a.x * SCALE, a.y * SCALE);
            u.y = pack2(a.z * SCALE, a.w * SCALE);
            u.z = pack2(bb.x * SCALE, bb.y * SCALE);
            u.w = pack2(bb.z * SCALE, bb.w * SCALE);
            qf[c] = __builtin_bit_cast(bf16x8, u);
        }
    }

    if (nt > 0) {
#pragma unroll
        for (int i = 0; i < 4; ++i) {
            const int cid = i * 256 + tid;
            const int d8 = cid & 31, row = cid >> 5;
            const float* src = Kg + (((size_t)b * LKg + row) * DDg + d8 * 8);
            float4 a = *(const float4*)src;
            float4 c = *(const float4*)(src + 4);
            uint4 u;
            u.x = pack2(a.x, a.y); u.y = pack2(a.z, a.w);
            u.z = pack2(c.x, c.y); u.w = pack2(c.z, c.w);
            *(uint4*)(&sK[0][row * 512 + ((d8 * 16) ^ ((row & 7) << 4))]) = u;
        }
        {
            const int dv = tid;
            const uint rot = 4 * ((dv >> 1) & 15);
            const float* src = Vg + (size_t)b * LKg * DDg + dv;
            uchar* dst = &sV[0][dv * 64];
#pragma unroll
            for (int kq = 0; kq < 8; ++kq) {
                float v0 = src[(kq * 4 + 0) * DDg];
                float v1 = src[(kq * 4 + 1) * DDg];
                float v2 = src[(kq * 4 + 2) * DDg];
                float v3 = src[(kq * 4 + 3) * DDg];
                const uint o = (8 * kq + rot) & 63;
                *(uint*)(dst + o) = pack2(v0, v1);
                *(uint*)(dst + ((o + 4) & 63)) = pack2(v2, v3);
            }
        }
    }

    f32x16 acc[8];
#pragma unroll
    for (int i = 0; i < 8; ++i)
#pragma unroll
        for (int j = 0; j < 16; ++j) acc[i][j] = 0.f;

    float m = -1e30f, ell = 0.f;
    const int swzK = (lq & 7) << 4;
    const int rotv = (lq >> 1) * 4;
    int cur = 0;

    __syncthreads();

    for (int t = 0; t < nt; ++t) {
        const int k0 = t * KVB;
        if (t + 1 < nt) {
            const int k1 = (t + 1) * KVB;
#pragma unroll
            for (int j = 0; j < 4; ++j) {
                const int cid = j * 256 + tid;
                const int d8 = cid & 31, row = cid >> 5;
                const float* src = Kg + (((size_t)b * LKg + k1 + row) * DDg + d8 * 8);
                float4 a = *(const float4*)src;
                float4 c = *(const float4*)(src + 4);
                uint4 u;
                u.x = pack2(a.x, a.y); u.y = pack2(a.z, a.w);
                u.z = pack2(c.x, c.y); u.w = pack2(c.z, c.w);
                *(uint4*)(&sK[cur ^ 1][row * 512 + ((d8 * 16) ^ ((row & 7) << 4))]) = u;
            }
            {
                const int dv = tid;
                const uint rot = 4 * ((dv >> 1) & 15);
                const float* src = Vg + ((size_t)b * LKg + k1) * DDg + dv;
                uchar* dst = &sV[cur ^ 1][dv * 64];
#pragma unroll
                for (int kq = 0; kq < 8; ++kq) {
                    float v0 = src[(kq * 4 + 0) * DDg];
                    float v1 = src[(kq * 4 + 1) * DDg];
                    float v2 = src[(kq * 4 + 2) * DDg];
                    float v3 = src[(kq * 4 + 3) * DDg];
                    const uint o = (8 * kq + rot) & 63;
                    *(uint*)(dst + o) = pack2(v0, v1);
                    *(uint*)(dst + ((o + 4) & 63)) = pack2(v2, v3);
                }
            }
        }

        const uchar* sKc = sK[cur];
        const uchar* sVc = sV[cur];
        f32x16 s0;
#pragma unroll
        for (int j = 0; j < 16; ++j) s0[j] = 0.f;
#pragma unroll
        for (int c = 0; c < 16; ++c) {
            bf16x8 kf = *(const bf16x8*)(sKc + lq * 512 + ((c * 32 + h * 16) ^ swzK));
            s0 = mfma32(kf, qf[c], s0);
        }

        if (k0 + KVB > vl) {
            const int kb0 = k0 + 4 * h;
#pragma unroll
            for (int r = 0; r < 16; ++r) {
                const int key0 = kb0 + (r & 3) + 8 * (r >> 2);
                if (key0 >= vl) s0[r] = 0.f;
            }
        }

        float mt = s0[0];
#pragma unroll
        for (int r = 1; r < 16; ++r) mt = fmaxf(mt, s0[r]);
        mt = fmaxf(mt, __shfl_xor(mt, 32));
        if (mt > m + 8.f) {
            const float mn = fmaxf(m, mt);
            const float sf = exp2f(m - mn);
            ell *= sf;
#pragma unroll
            for (int i2 = 0; i2 < 8; ++i2) acc[i2] *= sf;
            m = mn;
        }
        float rs = 0.f;
#pragma unroll
        for (int r = 0; r < 16; ++r) { s0[r] = exp2f(s0[r] - m); rs += s0[r]; }
        rs += __shfl_xor(rs, 32);
        ell += rs;

        bf16x8 pf[2];
#pragma unroll
        for (int kc = 0; kc < 2; ++kc) {
            const int bb = kc * 8;
            uint w0 = pack2(s0[bb + 0], s0[bb + 1]);
            uint w1 = pack2(s0[bb + 2], s0[bb + 3]);
            uint w2 = pack2(s0[bb + 4], s0[bb + 5]);
            uint w3 = pack2(s0[bb + 6], s0[bb + 7]);
            uint e0 = __shfl_xor(w0, 32);
            uint e1 = __shfl_xor(w1, 32);
            uint e2 = __shfl_xor(w2, 32);
            uint e3 = __shfl_xor(w3, 32);
            uint4 u;
            u.x = h ? e2 : w0;
            u.y = h ? e3 : w1;
            u.z = h ? w2 : e0;
            u.w = h ? w3 : e1;
            pf[kc] = __builtin_bit_cast(bf16x8, u);
        }

#pragma unroll
        for (int kc = 0; kc < 2; ++kc) {
            const int kk = kc * 16 + h * 8;
            const uint o0 = (uint)((2 * kk + rotv) & 63);
            const uint o1 = (uint)((2 * kk + 4 + rotv) & 63);
            const uint o2 = (uint)((2 * kk + 8 + rotv) & 63);
            const uint o3 = (uint)((2 * kk + 12 + rotv) & 63);
#pragma unroll
            for (int dt = 0; dt < 8; ++dt) {
                const uchar* base = sVc + dt * 2048 + lq * 64;
                uint4 u;
                u.x = *(const uint*)(base + o0);
                u.y = *(const uint*)(base + o1);
                u.z = *(const uint*)(base + o2);
                u.w = *(const uint*)(base + o3);
                acc[dt] = mfma32(__builtin_bit_cast(bf16x8, u), pf[kc], acc[dt]);
            }
        }

        __syncthreads();
        cur ^= 1;
    }

    if (use_tail) {
        const int bnd = nt * KVB;
        const int cnt = LKg - bnd;
        if (cnt > 0) {
            if (m < -8.f) {
                const float sf = exp2f(m);
                ell *= sf;
#pragma unroll
                for (int i = 0; i < 8; ++i) acc[i] *= sf;
                m = 0.f;
            }
            const float pt = exp2f(-m);
            ell += (float)cnt * pt;
            const float* tp = TV + b * DDg + h * 4;
#pragma unroll
            for (int dt = 0; dt < 8; ++dt) {
#pragma unroll
                for (int rg = 0; rg < 4; ++rg) {
                    float4 tv = *(const float4*)(tp + dt * 32 + rg * 8);
                    acc[dt][rg * 4 + 0] += pt * tv.x;
                    acc[dt][rg * 4 + 1] += pt * tv.y;
                    acc[dt][rg * 4 + 2] += pt * tv.z;
                    acc[dt][rg * 4 + 3] += pt * tv.w;
                }
            }
        }
    }
    const float inv = 1.f / ell;
    float* op = Og + ((size_t)(b * LQg + q)) * DDg + h * 4;
#pragma unroll
    for (int dt = 0; dt < 8; ++dt) {
#pragma unroll
        for (int rg = 0; rg < 4; ++rg) {
            float4 o;
            o.x = acc[dt][rg * 4 + 0] * inv;
            o.y = acc[dt][rg * 4 + 1] * inv;
            o.z = acc[dt][rg * 4 + 2] * inv;
            o.w = acc[dt][rg * 4 + 3] * inv;
            *(float4*)(op + dt * 32 + rg * 8) = o;
        }
    }
}

extern "C" void kernel_launch(void* const* d_in, const int* in_sizes, int n_in,
                              void* d_out, int out_size, void* d_ws, size_t ws_size,
                              hipStream_t stream) {
    const float* Q = (const float*)d_in[0];
    const float* K = (const float*)d_in[1];
    const float* V = (const float*)d_in[2];
    const int* vlen = (const int*)d_in[3];
    float* out = (float*)d_out;

    // ws layout: part(256KB) | TV(pad 256KB) | Kimg(16MB) | Vimg(16MB)
    const size_t off_part = 0;
    const size_t off_TV = 262144;
    const size_t off_K = 524288;
    const size_t imgsz = (size_t)NBg * NTILES << TSH;   // 16 MB
    const size_t off_V = off_K + imgsz;
    const size_t need_tail = off_TV + (size_t)NBg * DDg * 4;
    const size_t need_img = off_V + imgsz;              // 32.5 MB (proven fits)

    const int use_tail = (ws_size >= need_tail) ? 1 : 0;
    const int use_img = (ws_size >= need_img) ? 1 : 0;

    float* part = (float*)((char*)d_ws + off_part);
    float* TV = (float*)((char*)d_ws + off_TV);
    uchar* Kimg = (uchar*)d_ws + off_K;
    uchar* Vimg = (uchar*)d_ws + off_V;

    if (use_tail) {
        tv_partial_k<<<dim3(16, 16), 256, 0, stream>>>(V, vlen, part);
        tv_reduce_k<<<dim3(16), 256, 0, stream>>>(part, TV);
    }
    if (use_img) {
        prep_k<<<dim3(4096), 256, 0, stream>>>(K, Kimg);
        prep_v<<<dim3(1024), 256, 0, stream>>>(V, Vimg);
        // 1024 independent 1-wave blocks, no LDS, no barriers
        attn_img_k<<<dim3(1024), 64, 0, stream>>>(Q, Kimg, Vimg, vlen, TV, out, use_tail);
    } else {
        attn_fb_k<<<dim3(256), 256, 0, stream>>>(Q, K, V, vlen, TV, out, use_tail);
    }
}